// Round 16
// baseline (621.570 us; speedup 1.0000x reference)
//
#include <hip/hip_runtime.h>

typedef __attribute__((ext_vector_type(4))) int  i8x16;   // 16 packed int8 (4 VGPR MFMA operand)
typedef __attribute__((ext_vector_type(4))) int  i32x4;   // 16x16 i32 accumulator
typedef __attribute__((ext_vector_type(8))) short bf16x8;
typedef __attribute__((ext_vector_type(8))) unsigned short ushort8;
typedef __attribute__((ext_vector_type(4))) float f32x4;

__device__ __forceinline__ unsigned short f32_to_bf16(float f) {
    union { float f; unsigned int u; } v;
    v.f = f;
    unsigned int r = v.u + (0x7fffu + ((v.u >> 16) & 1u));
    return (unsigned short)(r >> 16);
}

__device__ __forceinline__ void gload_lds16(const void* g, void* l) {
    __builtin_amdgcn_global_load_lds(
        (const __attribute__((address_space(1))) unsigned int*)g,
        (__attribute__((address_space(3))) unsigned int*)l, 16, 0, 0);
}

// ---------------- x -> int8 per-row symmetric quantization ----------------
__global__ __launch_bounds__(256) void quantx_kernel(const float* __restrict__ x,
                                                     char* __restrict__ xq,
                                                     float* __restrict__ rs, int K) {
    const int row = blockIdx.x;
    const float4* xr = (const float4*)(x + (size_t)row * K);
    const int K4 = K >> 2;
    const int t = threadIdx.x;
    float am = 0.f;
    for (int i = t; i < K4; i += 256) {
        float4 v = xr[i];
        am = fmaxf(am, fmaxf(fmaxf(fabsf(v.x), fabsf(v.y)),
                             fmaxf(fabsf(v.z), fabsf(v.w))));
    }
    for (int off = 32; off; off >>= 1) am = fmaxf(am, __shfl_xor(am, off));
    __shared__ float ws[4];
    if ((t & 63) == 0) ws[t >> 6] = am;
    __syncthreads();
    am = fmaxf(fmaxf(ws[0], ws[1]), fmaxf(ws[2], ws[3]));
    const float inv = am > 0.f ? 127.f / am : 0.f;
    if (t == 0) rs[row] = am > 0.f ? am / 127.f : 0.f;
    int* dst = (int*)(xq + (size_t)row * K);
    for (int i = t; i < K4; i += 256) {
        float4 v = xr[i];
        int a = (int)rintf(v.x * inv), b = (int)rintf(v.y * inv);
        int c = (int)rintf(v.z * inv), d = (int)rintf(v.w * inv);
        dst[i] = (a & 255) | ((b & 255) << 8) | ((c & 255) << 16) | (d << 24);
    }
}

// ---------------- qweight int32 -> int8 ----------------
__global__ void convq_kernel(const int* __restrict__ q, char* __restrict__ qb, long n16) {
    long i = (long)blockIdx.x * blockDim.x + threadIdx.x;
    const long stride = (long)gridDim.x * blockDim.x;
    for (; i < n16; i += stride) {
        const int4* p = (const int4*)(q + i * 16);
        int4 a = p[0], b = p[1], c = p[2], d = p[3];
        int4 r;
        r.x = (a.x & 255) | ((a.y & 255) << 8) | ((a.z & 255) << 16) | (a.w << 24);
        r.y = (b.x & 255) | ((b.y & 255) << 8) | ((b.z & 255) << 16) | (b.w << 24);
        r.z = (c.x & 255) | ((c.y & 255) << 8) | ((c.z & 255) << 16) | (c.w << 24);
        r.w = (d.x & 255) | ((d.y & 255) << 8) | ((d.z & 255) << 16) | (d.w << 24);
        ((int4*)qb)[i] = r;
    }
}

// ---------------- 256x256 i8 GEMM: A via LDS, B direct global->VGPR ---------
// C[m,n] = sum_k xq[m,k]*qb[n,k] (i32); out = C * rs[m]*scale[n] + bias[n]
// 512 thr, 8 waves (2wr x 4wc), per-wave 128x64, BK=128 bytes, NT=K/128 (even).
// Lever vs R11 (296us, MfmaUtil 40%): R11-R15 showed wall = LDS-cycles +
// matrix-cycles SUMMED. B moves out of LDS entirely: each wave loads its
// B-fragments global->VGPR one tile ahead (qb is L2/L3-resident, 2x wave
// redundancy only), dual register sets via 2x-unrolled loop (static idx,
// rule #20). LDS now carries A only: reads 192->128 b128/CU/tile, writes
// 64->32KB -> LDS ~1800 vs matrix 2614 cyc.
// Sync: ONE barrier/tile. Staging order: A-stage (4, oldest) -> B-loads (8)
// -> vmcnt(8) drains A-stage only, B rides across the barrier (consumed
// next tile via compiler register deps).
// A swizzle/layout identical to R11 (conflicts measured 0).
__global__ __launch_bounds__(512, 2) void qgemm_i8_kernel(
    const char* __restrict__ A, const char* __restrict__ B,
    const float* __restrict__ rs, const float* __restrict__ scale,
    const float* __restrict__ bias, float* __restrict__ C, int M, int N, int K) {
    extern __shared__ char sm[];   // 64KB: A dbuf 2x32KB @0/32768

    const int tid  = threadIdx.x;
    const int lane = tid & 63;
    const int w    = tid >> 6;
    const int wr   = w >> 2;                  // 0..1
    const int wc   = w & 3;                   // 0..3
    const int l15  = lane & 15;
    const int l4   = lane >> 4;
    const int r7   = l15 & 7;

    // T1: bijective XCD swizzle (gridDim.x % 8 == 0 by construction)
    const int nwg = gridDim.x;
    const int bid = blockIdx.x;
    const int swz = (bid & 7) * (nwg >> 3) + (bid >> 3);
    const int nbx = N >> 8;
    const int m0  = (swz / nbx) << 8;
    const int n0  = (swz % nbx) << 8;

    // A staging (R11-proven): chunk c -> r=c>>3, s=(c&7)^(r&7); src = r*K+s*16
    const int c0 = tid, c1 = tid + 512;
    const size_t inv0 = (size_t)(c0 >> 3) * K + (size_t)((((c0 & 7) ^ ((c0 >> 3) & 7))) << 4);
    const size_t inv1 = (size_t)(c1 >> 3) * K + (size_t)((((c1 & 7) ^ ((c1 >> 3) & 7))) << 4);
    const int ldst0 = w << 10;
    const int ldst1 = (w << 10) + 8192;

#define STAGE_A(buf, gsrc) do {                           \
        gload_lds16((gsrc) + inv0, (buf) + ldst0);        \
        gload_lds16((gsrc) + inv1, (buf) + ldst1); } while (0)
    // full A tile = STAGE_A(buf, pA+k) ; STAGE_A(buf+16384, pA+hK+k)  [4 ops]

    // A fragment reads (R11-proven, conflict-free)
    const int aRow0 = (wr * 128 + l15) * 128;  // + m*2048
    const int sl0   = ((0 + l4) ^ r7) << 4;
    const int sl1   = ((4 + l4) ^ r7) << 4;

    const char* pA = A + (size_t)m0 * K;
    const size_t hK = (size_t)128 * K;
    const int NT = K >> 7;

    // B direct: lane l supplies col (n0+wc*64+nf*16+l15), k-bytes l4*16 (+kk*64)
    const char* pBl = B + (size_t)(n0 + wc * 64 + l15) * K + (l4 << 4);
    const size_t bStride = (size_t)K << 4;     // nf step = 16 rows

    i32x4 acc[8][4];
#pragma unroll
    for (int m = 0; m < 8; ++m)
#pragma unroll
        for (int n = 0; n < 4; ++n) acc[m][n] = (i32x4){0, 0, 0, 0};

#define LOADB(DST, T) do {                                                     \
    _Pragma("unroll") for (int nf = 0; nf < 4; ++nf)                           \
    _Pragma("unroll") for (int kk = 0; kk < 2; ++kk)                           \
        (DST)[nf][kk] = *(const i8x16*)(pBl + (size_t)nf * bStride +           \
                                        (size_t)(T) * 128 + kk * 64); } while (0)
#define RD_A(DST, BUF, MB)                                                     \
    _Pragma("unroll") for (int m = 0; m < 4; ++m) {                            \
        (DST)[m][0] = *(const i8x16*)((BUF) + aRow0 + ((MB) + m) * 2048 + sl0); \
        (DST)[m][1] = *(const i8x16*)((BUF) + aRow0 + ((MB) + m) * 2048 + sl1); }
#define MFMA_H(AF, BC, MB)                                                     \
    _Pragma("unroll") for (int kk = 0; kk < 2; ++kk)                           \
    _Pragma("unroll") for (int m = 0; m < 4; ++m)                              \
    _Pragma("unroll") for (int nf = 0; nf < 4; ++nf)                           \
        acc[(MB) + m][nf] = __builtin_amdgcn_mfma_i32_16x16x64_i8(             \
            (AF)[m][kk], (BC)[nf][kk], acc[(MB) + m][nf], 0, 0, 0);
#define LGKM0() do { asm volatile("s_waitcnt lgkmcnt(0)" ::: "memory");        \
                     __builtin_amdgcn_sched_barrier(0); } while (0)

    i8x16 aF0[4][2], aF1[4][2], bX[4][2], bY[4][2];

    // ---- prologue: A(0) -> LDS buf0 (4 ops, oldest); B(0) -> bX (8 ops) ----
    STAGE_A(sm,         pA);
    STAGE_A(sm + 16384, pA + hK);
    LOADB(bX, 0);
    asm volatile("s_waitcnt vmcnt(8)" ::: "memory");   // A(0) landed; B in flight
    __builtin_amdgcn_s_barrier();

#define TILE(T, AB, AN, BCUR, BNXT) do {                                       \
        const int k1_ = ((T) + 1) << 7;                                        \
        if ((T) + 1 < NT) {                                                    \
            STAGE_A((AN),         pA + k1_);          /* 4 ops, oldest */      \
            STAGE_A((AN) + 16384, pA + hK + k1_);                              \
            LOADB(BNXT, (T) + 1);                     /* 8 ops, newest */      \
        }                                                                      \
        RD_A(aF0, (AB), 0);                                                    \
        LGKM0();                                                               \
        __builtin_amdgcn_s_setprio(1);                                         \
        MFMA_H(aF0, BCUR, 0);                                                  \
        __builtin_amdgcn_s_setprio(0);                                         \
        RD_A(aF1, (AB), 4);                                                    \
        LGKM0();                                                               \
        __builtin_amdgcn_s_setprio(1);                                         \
        MFMA_H(aF1, BCUR, 4);                                                  \
        __builtin_amdgcn_s_setprio(0);                                         \
        if ((T) + 1 < NT) asm volatile("s_waitcnt vmcnt(8)" ::: "memory");     \
        else              asm volatile("s_waitcnt vmcnt(0)" ::: "memory");     \
        __builtin_amdgcn_s_barrier();  /* publish A(T+1); guard re-stage */    \
    } while (0)

    // NT is even (launcher guards K % 256 == 0)
    for (int t = 0; t < NT; t += 2) {
        char* Ab = sm + (t & 2 ? 32768 : 0);        // t%2==0 buf = (t/1)&1... t even: buf t&1=0 -> alternate by t
        // NOTE: buffer parity = t&1; with t even here, cur = (t>>1&1)? -- use direct:
        char* cur = sm + ((t & 1) ? 32768 : 0);     // t even -> buf0? No: tiles alternate every tile.
        (void)Ab; (void)cur;
        char* b0 = sm + ((t & 1) * 32768);          // == sm (t even)
        char* b1 = sm + (((t + 1) & 1) * 32768);    // == sm+32768
        TILE(t,     b0, b1, bX, bY);
        TILE(t + 1, b1, b0, bY, bX);
    }

    // ---- epilogue: out = acc * (rs[row]*scale[col]) + bias[col] ----
    // C/D 16x16 layout: col = l15, row = l4*4 + j
#pragma unroll
    for (int n = 0; n < 4; ++n) {
        const int col = n0 + wc * 64 + n * 16 + l15;
        const float sc = scale[col];
        const float bs = bias[col];
#pragma unroll
        for (int m = 0; m < 8; ++m) {
            const int row0 = m0 + wr * 128 + m * 16 + l4 * 4;
#pragma unroll
            for (int j = 0; j < 4; ++j)
                C[(size_t)(row0 + j) * N + col] =
                    (float)acc[m][n][j] * (rs[row0 + j] * sc) + bs;
        }
    }
#undef STAGE_A
#undef LOADB
#undef RD_A
#undef MFMA_H
#undef LGKM0
#undef TILE
}

// ---------------- fallback (shape mismatch): 2-phase bf16, on-the-fly ----
__global__ __launch_bounds__(256) void qgemm_fb_kernel(
    const float* __restrict__ Af, const int* __restrict__ Bi,
    const float* __restrict__ scale, const float* __restrict__ bias,
    float* __restrict__ C, int M, int N, int K) {
    constexpr int BK = 64;
    __shared__ unsigned short lA[128 * BK];
    __shared__ unsigned short lB[128 * BK];
    const int t = threadIdx.x, lane = t & 63, w = t >> 6;
    const int wr = w >> 1, wc = w & 1;
    const int m0 = blockIdx.y * 128, n0 = blockIdx.x * 128;
    const int l15 = lane & 15, l4 = lane >> 4;
    f32x4 acc[4][4];
#pragma unroll
    for (int m = 0; m < 4; ++m)
#pragma unroll
        for (int n = 0; n < 4; ++n) acc[m][n] = (f32x4){0.f, 0.f, 0.f, 0.f};
    for (int k0 = 0; k0 < K; k0 += BK) {
        __syncthreads();
#pragma unroll
        for (int i = 0; i < 4; ++i) {
            const int off = i * 4096 + w * 1024 + lane * 16;
            const int row = off >> 7;
            const int col = (off & 127) >> 1;
            const float* pa = Af + (size_t)(m0 + row) * K + k0 + col;
            float4 a0 = *(const float4*)pa;
            float4 a1 = *(const float4*)(pa + 4);
            ushort8 va;
            va[0] = f32_to_bf16(a0.x); va[1] = f32_to_bf16(a0.y);
            va[2] = f32_to_bf16(a0.z); va[3] = f32_to_bf16(a0.w);
            va[4] = f32_to_bf16(a1.x); va[5] = f32_to_bf16(a1.y);
            va[6] = f32_to_bf16(a1.z); va[7] = f32_to_bf16(a1.w);
            *(ushort8*)((char*)lA + off) = va;
            const int* pb = Bi + (size_t)(n0 + row) * K + k0 + col;
            int4 b0 = *(const int4*)pb;
            int4 b1 = *(const int4*)(pb + 4);
            ushort8 vb;
            vb[0] = f32_to_bf16((float)b0.x); vb[1] = f32_to_bf16((float)b0.y);
            vb[2] = f32_to_bf16((float)b0.z); vb[3] = f32_to_bf16((float)b0.w);
            vb[4] = f32_to_bf16((float)b1.x); vb[5] = f32_to_bf16((float)b1.y);
            vb[6] = f32_to_bf16((float)b1.z); vb[7] = f32_to_bf16((float)b1.w);
            *(ushort8*)((char*)lB + off) = vb;
        }
        __syncthreads();
#pragma unroll
        for (int kk = 0; kk < BK; kk += 32) {
            bf16x8 af[4], bfr[4];
#pragma unroll
            for (int m = 0; m < 4; ++m)
                af[m] = *(const bf16x8*)&lA[(wr * 64 + m * 16 + l15) * BK + kk + l4 * 8];
#pragma unroll
            for (int n = 0; n < 4; ++n)
                bfr[n] = *(const bf16x8*)&lB[(wc * 64 + n * 16 + l15) * BK + kk + l4 * 8];
#pragma unroll
            for (int m = 0; m < 4; ++m)
#pragma unroll
                for (int n = 0; n < 4; ++n)
                    acc[m][n] = __builtin_amdgcn_mfma_f32_16x16x32_bf16(
                        af[m], bfr[n], acc[m][n], 0, 0, 0);
        }
    }
#pragma unroll
    for (int n = 0; n < 4; ++n) {
        const int col = n0 + wc * 64 + n * 16 + l15;
        const float sc = scale[col], bs = bias[col];
#pragma unroll
        for (int m = 0; m < 4; ++m) {
            const int row0 = m0 + wr * 64 + m * 16 + l4 * 4;
#pragma unroll
            for (int j = 0; j < 4; ++j)
                C[(size_t)(row0 + j) * N + col] = fmaf(acc[m][n][j], sc, bs);
        }
    }
}

extern "C" void kernel_launch(void* const* d_in, const int* in_sizes, int n_in,
                              void* d_out, int out_size, void* d_ws, size_t ws_size,
                              hipStream_t stream) {
    const float* x     = (const float*)d_in[0];
    const int*   q     = (const int*)d_in[1];
    const float* scale = (const float*)d_in[2];
    const float* bias  = (const float*)d_in[3];
    float*       out   = (float*)d_out;

    const int K = in_sizes[2];
    const int N = in_sizes[1] / K;
    const int M = in_sizes[0] / K;

    const size_t xq_b = (size_t)M * K;
    const size_t qb_b = (size_t)N * K;
    const size_t need = xq_b + qb_b + (size_t)M * 4;
    const int nwg = (M / 256) * (N / 256);

    if (ws_size >= need && (M % 256) == 0 && (N % 256) == 0 &&
        (K % 256) == 0 && (nwg % 8) == 0) {
        char*  xq = (char*)d_ws;
        char*  qb = xq + xq_b;
        float* rs = (float*)(qb + qb_b);
        quantx_kernel<<<M, 256, 0, stream>>>(x, xq, rs, K);
        convq_kernel<<<2048, 256, 0, stream>>>(q, qb, (long)(qb_b / 16));
        qgemm_i8_kernel<<<nwg, 512, 65536, stream>>>(xq, qb, rs, scale, bias,
                                                     out, M, N, K);
    } else {
        dim3 grid(N / 128, M / 128);
        qgemm_fb_kernel<<<grid, 256, 0, stream>>>(x, q, scale, bias, out, M, N, K);
    }
}

// Round 17
// 513.875 us; speedup vs baseline: 1.2096x; 1.2096x over previous
//
#include <hip/hip_runtime.h>

typedef __attribute__((ext_vector_type(4))) int  i8x16;   // 16 packed int8 (4 VGPR MFMA operand)
typedef __attribute__((ext_vector_type(4))) int  i32x4;   // 16x16 i32 accumulator
typedef __attribute__((ext_vector_type(8))) short bf16x8;
typedef __attribute__((ext_vector_type(8))) unsigned short ushort8;
typedef __attribute__((ext_vector_type(4))) float f32x4;

__device__ __forceinline__ unsigned short f32_to_bf16(float f) {
    union { float f; unsigned int u; } v;
    v.f = f;
    unsigned int r = v.u + (0x7fffu + ((v.u >> 16) & 1u));
    return (unsigned short)(r >> 16);
}

__device__ __forceinline__ void gload_lds16(const void* g, void* l) {
    __builtin_amdgcn_global_load_lds(
        (const __attribute__((address_space(1))) unsigned int*)g,
        (__attribute__((address_space(3))) unsigned int*)l, 16, 0, 0);
}

// ---------------- x -> int8 per-row symmetric quantization ----------------
__global__ __launch_bounds__(256) void quantx_kernel(const float* __restrict__ x,
                                                     char* __restrict__ xq,
                                                     float* __restrict__ rs, int K) {
    const int row = blockIdx.x;
    const float4* xr = (const float4*)(x + (size_t)row * K);
    const int K4 = K >> 2;
    const int t = threadIdx.x;
    float am = 0.f;
    for (int i = t; i < K4; i += 256) {
        float4 v = xr[i];
        am = fmaxf(am, fmaxf(fmaxf(fabsf(v.x), fabsf(v.y)),
                             fmaxf(fabsf(v.z), fabsf(v.w))));
    }
    for (int off = 32; off; off >>= 1) am = fmaxf(am, __shfl_xor(am, off));
    __shared__ float ws[4];
    if ((t & 63) == 0) ws[t >> 6] = am;
    __syncthreads();
    am = fmaxf(fmaxf(ws[0], ws[1]), fmaxf(ws[2], ws[3]));
    const float inv = am > 0.f ? 127.f / am : 0.f;
    if (t == 0) rs[row] = am > 0.f ? am / 127.f : 0.f;
    int* dst = (int*)(xq + (size_t)row * K);
    for (int i = t; i < K4; i += 256) {
        float4 v = xr[i];
        int a = (int)rintf(v.x * inv), b = (int)rintf(v.y * inv);
        int c = (int)rintf(v.z * inv), d = (int)rintf(v.w * inv);
        dst[i] = (a & 255) | ((b & 255) << 8) | ((c & 255) << 16) | (d << 24);
    }
}

// ---------------- qweight int32 -> int8 ----------------
__global__ void convq_kernel(const int* __restrict__ q, char* __restrict__ qb, long n16) {
    long i = (long)blockIdx.x * blockDim.x + threadIdx.x;
    const long stride = (long)gridDim.x * blockDim.x;
    for (; i < n16; i += stride) {
        const int4* p = (const int4*)(q + i * 16);
        int4 a = p[0], b = p[1], c = p[2], d = p[3];
        int4 r;
        r.x = (a.x & 255) | ((a.y & 255) << 8) | ((a.z & 255) << 16) | (a.w << 24);
        r.y = (b.x & 255) | ((b.y & 255) << 8) | ((b.z & 255) << 16) | (b.w << 24);
        r.z = (c.x & 255) | ((c.y & 255) << 8) | ((c.z & 255) << 16) | (c.w << 24);
        r.w = (d.x & 255) | ((d.y & 255) << 8) | ((d.z & 255) << 16) | (d.w << 24);
        ((int4*)qb)[i] = r;
    }
}

// ---------------- 256x256 i8 GEMM, 4 FAT waves (128x128 each) ---------------
// C[m,n] = sum_k xq[m,k]*qb[n,k] (i32); out = C * rs[m]*scale[n] + bias[n]
// 256 thr = 4 waves (2wr x 2wc), per-wave 128x128 = 8mf x 8nf 16x16 frags.
// WHY vs R11 (296us, 8 thin waves): LDS instr count = waves*(m+n)/16 per K64.
// 8 waves of 128x64 -> 192 b128/CU/tile (4x A redundancy); 4 waves of 128x128
// -> 128 b128/CU/tile (2x redundancy) = -33% LDS work, same MFMA work.
// acc = 256 VGPR -> needs 1 wave/SIMD (unified budget 512, m08/m24: no
// spill <=450). Total live ~410: acc 256 + dual frag sets 128 + addr.
// kk1 reads are issued before kk0's MFMA (counted LGKM<=15, dual sets) so
// the LDS queue drains during the MFMA window even at 1 wave/SIMD.
// LDS 128KB: A dbuf 2x32KB @0/32768, B dbuf 2x32KB @65536/98304.
// Layout/swizzle byte-identical to R11 (conflicts measured 0): 128B rows,
// chunk (r,s) at slot s^(r&7); frag slot kk*4+l4 ^ (l15&7).
__global__ __launch_bounds__(256, 1) void qgemm_i8_kernel(
    const char* __restrict__ A, const char* __restrict__ B,
    const float* __restrict__ rs, const float* __restrict__ scale,
    const float* __restrict__ bias, float* __restrict__ C, int M, int N, int K) {
    extern __shared__ char sm[];

    const int tid  = threadIdx.x;
    const int lane = tid & 63;
    const int w    = tid >> 6;                // 0..3
    const int wr   = w >> 1;                  // 0..1
    const int wc   = w & 1;                   // 0..1
    const int l15  = lane & 15;
    const int l4   = lane >> 4;
    const int r7   = l15 & 7;

    // T1: bijective XCD swizzle (gridDim.x % 8 == 0 by construction)
    const int nwg = gridDim.x;
    const int bid = blockIdx.x;
    const int swz = (bid & 7) * (nwg >> 3) + (bid >> 3);
    const int nbx = N >> 8;
    const int m0  = (swz / nbx) << 8;
    const int n0  = (swz % nbx) << 8;

    // staging: 256 thr x 8 rounds cover 2048 chunks (32KB). chunk c = tid+256j:
    // r = c>>3 = (tid>>3)+32j, s = tid&7; f(r) = (r&7) = (tid>>3)&7 (32j drops).
    const size_t inv0 = (size_t)(tid >> 3) * K +
                        (size_t)(((tid & 7) ^ ((tid >> 3) & 7)) << 4);
    const int ldsW = w << 10;                 // wave-uniform base within round

#define STAGE_T(buf, gsrc) do {                                               \
    _Pragma("unroll") for (int j = 0; j < 8; ++j)                             \
        gload_lds16((gsrc) + inv0 + (size_t)(32 * j) * K,                     \
                    (buf) + j * 4096 + ldsW); } while (0)

    // fragment read offsets (bytes), R11-proven conflict-free
    const int aRow0 = (wr * 128 + l15) * 128;  // + mf*2048
    const int bRow0 = (wc * 128 + l15) * 128;  // + nf*2048
    const int sl0   = ((0 + l4) ^ r7) << 4;    // kk0: k-bytes 0-63
    const int sl1   = ((4 + l4) ^ r7) << 4;    // kk1: k-bytes 64-127

    const char* pA = A + (size_t)m0 * K;
    const char* pB = B + (size_t)n0 * K;
    const int NT = K >> 7;                     // 128 bytes of K per tile

    i32x4 acc[8][8];
#pragma unroll
    for (int m = 0; m < 8; ++m)
#pragma unroll
        for (int n = 0; n < 8; ++n) acc[m][n] = (i32x4){0, 0, 0, 0};

#define RD8(DST, BUF, ROW0, SL)                                               \
    _Pragma("unroll") for (int f = 0; f < 8; ++f)                             \
        (DST)[f] = *(const i8x16*)((BUF) + (ROW0) + f * 2048 + (SL));
#define MFMA64(AF, BF)                                                        \
    _Pragma("unroll") for (int m = 0; m < 8; ++m)                             \
    _Pragma("unroll") for (int n = 0; n < 8; ++n)                             \
        acc[m][n] = __builtin_amdgcn_mfma_i32_16x16x64_i8(                    \
            (AF)[m], (BF)[n], acc[m][n], 0, 0, 0);
#define LGKM(NM) do { asm volatile("s_waitcnt lgkmcnt(" #NM ")" ::: "memory");\
                      __builtin_amdgcn_sched_barrier(0); } while (0)

    i8x16 aF0[8], aF1[8], bF0[8], bF1[8];

    // ---- prologue: stage tile0 (16) + tile1 (16); 16 stay in flight ----
    STAGE_T(sm + 0,     pA);                  // A(0)
    STAGE_T(sm + 65536, pB);                  // B(0)
    if (NT > 1) {
        STAGE_T(sm + 32768, pA + 128);        // A(1)
        STAGE_T(sm + 98304, pB + 128);        // B(1)
        asm volatile("s_waitcnt vmcnt(16)" ::: "memory");  // tile0 landed
    } else {
        asm volatile("s_waitcnt vmcnt(0)" ::: "memory");
    }
    __builtin_amdgcn_s_barrier();

    for (int t = 0; t < NT; ++t) {
        char* Ab = sm + (t & 1) * 32768;
        char* Bb = sm + 65536 + (t & 1) * 32768;

        // issue kk0 (16 reads) then kk1 (16 reads); wait kk0 (15 ok: 17/32
        // done = all kk0 + 1 kk1); MFMA kk0 overlaps kk1's queue drain.
        RD8(aF0, Ab, aRow0, sl0);
        RD8(bF0, Bb, bRow0, sl0);
        RD8(aF1, Ab, aRow0, sl1);
        RD8(bF1, Bb, bRow0, sl1);
        LGKM(15);
        __builtin_amdgcn_s_setprio(1);
        MFMA64(aF0, bF0);
        __builtin_amdgcn_s_setprio(0);
        LGKM(0);
        __builtin_amdgcn_s_setprio(1);
        MFMA64(aF1, bF1);
        __builtin_amdgcn_s_setprio(0);

        if (t + 1 < NT) {
            __builtin_amdgcn_s_barrier();   // B1: all waves done reading cur
            if (t + 2 < NT) {
                STAGE_T(Ab, pA + (size_t)(t + 2) * 128);
                STAGE_T(Bb, pB + (size_t)(t + 2) * 128);
                asm volatile("s_waitcnt vmcnt(16)" ::: "memory");  // t+1 landed
            } else {
                asm volatile("s_waitcnt vmcnt(0)" ::: "memory");
            }
            __builtin_amdgcn_s_barrier();   // B2: publish tile t+1
        }
    }

    // ---- epilogue: out = acc * (rs[row]*scale[col]) + bias[col] ----
    // C/D 16x16 layout: col = l15, row = l4*4 + j
#pragma unroll
    for (int n = 0; n < 8; ++n) {
        const int col = n0 + wc * 128 + n * 16 + l15;
        const float sc = scale[col];
        const float bs = bias[col];
#pragma unroll
        for (int m = 0; m < 8; ++m) {
            const int row0 = m0 + wr * 128 + m * 16 + l4 * 4;
#pragma unroll
            for (int j = 0; j < 4; ++j)
                C[(size_t)(row0 + j) * N + col] =
                    (float)acc[m][n][j] * (rs[row0 + j] * sc) + bs;
        }
    }
#undef STAGE_T
#undef RD8
#undef MFMA64
#undef LGKM
}

// ---------------- fallback (shape mismatch): 2-phase bf16, on-the-fly ----
__global__ __launch_bounds__(256) void qgemm_fb_kernel(
    const float* __restrict__ Af, const int* __restrict__ Bi,
    const float* __restrict__ scale, const float* __restrict__ bias,
    float* __restrict__ C, int M, int N, int K) {
    constexpr int BK = 64;
    __shared__ unsigned short lA[128 * BK];
    __shared__ unsigned short lB[128 * BK];
    const int t = threadIdx.x, lane = t & 63, w = t >> 6;
    const int wr = w >> 1, wc = w & 1;
    const int m0 = blockIdx.y * 128, n0 = blockIdx.x * 128;
    const int l15 = lane & 15, l4 = lane >> 4;
    f32x4 acc[4][4];
#pragma unroll
    for (int m = 0; m < 4; ++m)
#pragma unroll
        for (int n = 0; n < 4; ++n) acc[m][n] = (f32x4){0.f, 0.f, 0.f, 0.f};
    for (int k0 = 0; k0 < K; k0 += BK) {
        __syncthreads();
#pragma unroll
        for (int i = 0; i < 4; ++i) {
            const int off = i * 4096 + w * 1024 + lane * 16;
            const int row = off >> 7;
            const int col = (off & 127) >> 1;
            const float* pa = Af + (size_t)(m0 + row) * K + k0 + col;
            float4 a0 = *(const float4*)pa;
            float4 a1 = *(const float4*)(pa + 4);
            ushort8 va;
            va[0] = f32_to_bf16(a0.x); va[1] = f32_to_bf16(a0.y);
            va[2] = f32_to_bf16(a0.z); va[3] = f32_to_bf16(a0.w);
            va[4] = f32_to_bf16(a1.x); va[5] = f32_to_bf16(a1.y);
            va[6] = f32_to_bf16(a1.z); va[7] = f32_to_bf16(a1.w);
            *(ushort8*)((char*)lA + off) = va;
            const int* pb = Bi + (size_t)(n0 + row) * K + k0 + col;
            int4 b0 = *(const int4*)pb;
            int4 b1 = *(const int4*)(pb + 4);
            ushort8 vb;
            vb[0] = f32_to_bf16((float)b0.x); vb[1] = f32_to_bf16((float)b0.y);
            vb[2] = f32_to_bf16((float)b0.z); vb[3] = f32_to_bf16((float)b0.w);
            vb[4] = f32_to_bf16((float)b1.x); vb[5] = f32_to_bf16((float)b1.y);
            vb[6] = f32_to_bf16((float)b1.z); vb[7] = f32_to_bf16((float)b1.w);
            *(ushort8*)((char*)lB + off) = vb;
        }
        __syncthreads();
#pragma unroll
        for (int kk = 0; kk < BK; kk += 32) {
            bf16x8 af[4], bfr[4];
#pragma unroll
            for (int m = 0; m < 4; ++m)
                af[m] = *(const bf16x8*)&lA[(wr * 64 + m * 16 + l15) * BK + kk + l4 * 8];
#pragma unroll
            for (int n = 0; n < 4; ++n)
                bfr[n] = *(const bf16x8*)&lB[(wc * 64 + n * 16 + l15) * BK + kk + l4 * 8];
#pragma unroll
            for (int m = 0; m < 4; ++m)
#pragma unroll
                for (int n = 0; n < 4; ++n)
                    acc[m][n] = __builtin_amdgcn_mfma_f32_16x16x32_bf16(
                        af[m], bfr[n], acc[m][n], 0, 0, 0);
        }
    }
#pragma unroll
    for (int n = 0; n < 4; ++n) {
        const int col = n0 + wc * 64 + n * 16 + l15;
        const float sc = scale[col], bs = bias[col];
#pragma unroll
        for (int m = 0; m < 4; ++m) {
            const int row0 = m0 + wr * 64 + m * 16 + l4 * 4;
#pragma unroll
            for (int j = 0; j < 4; ++j)
                C[(size_t)(row0 + j) * N + col] = fmaf(acc[m][n][j], sc, bs);
        }
    }
}

extern "C" void kernel_launch(void* const* d_in, const int* in_sizes, int n_in,
                              void* d_out, int out_size, void* d_ws, size_t ws_size,
                              hipStream_t stream) {
    const float* x     = (const float*)d_in[0];
    const int*   q     = (const int*)d_in[1];
    const float* scale = (const float*)d_in[2];
    const float* bias  = (const float*)d_in[3];
    float*       out   = (float*)d_out;

    const int K = in_sizes[2];
    const int N = in_sizes[1] / K;
    const int M = in_sizes[0] / K;

    const size_t xq_b = (size_t)M * K;
    const size_t qb_b = (size_t)N * K;
    const size_t need = xq_b + qb_b + (size_t)M * 4;
    const int nwg = (M / 256) * (N / 256);

    if (ws_size >= need && (M % 256) == 0 && (N % 256) == 0 &&
        (K % 128) == 0 && K >= 256 && (nwg % 8) == 0) {
        char*  xq = (char*)d_ws;
        char*  qb = xq + xq_b;
        float* rs = (float*)(qb + qb_b);
        quantx_kernel<<<M, 256, 0, stream>>>(x, xq, rs, K);
        convq_kernel<<<2048, 256, 0, stream>>>(q, qb, (long)(qb_b / 16));
        qgemm_i8_kernel<<<nwg, 256, 131072, stream>>>(xq, qb, rs, scale, bias,
                                                      out, M, N, K);
    } else {
        dim3 grid(N / 128, M / 128);
        qgemm_fb_kernel<<<grid, 256, 0, stream>>>(x, q, scale, bias, out, M, N, K);
    }
}

// Round 18
// 372.169 us; speedup vs baseline: 1.6701x; 1.3808x over previous
//
#include <hip/hip_runtime.h>

typedef __attribute__((ext_vector_type(4))) int  i8x16;   // 16 packed int8 (4 VGPR MFMA operand)
typedef __attribute__((ext_vector_type(4))) int  i32x4;   // 16x16 i32 accumulator
typedef __attribute__((ext_vector_type(8))) short bf16x8;
typedef __attribute__((ext_vector_type(8))) unsigned short ushort8;
typedef __attribute__((ext_vector_type(4))) float f32x4;

__device__ __forceinline__ unsigned short f32_to_bf16(float f) {
    union { float f; unsigned int u; } v;
    v.f = f;
    unsigned int r = v.u + (0x7fffu + ((v.u >> 16) & 1u));
    return (unsigned short)(r >> 16);
}

__device__ __forceinline__ void gload_lds16(const void* g, void* l) {
    __builtin_amdgcn_global_load_lds(
        (const __attribute__((address_space(1))) unsigned int*)g,
        (__attribute__((address_space(3))) unsigned int*)l, 16, 0, 0);
}

// ---------------- x -> int8 per-row quant, LDS row cache (single read) ------
__global__ __launch_bounds__(256) void quantx_lds_kernel(const float* __restrict__ x,
                                                         char* __restrict__ xq,
                                                         float* __restrict__ rs, int K) {
    extern __shared__ float rowbuf[];          // K floats
    const int row = blockIdx.x;
    const float4* xr = (const float4*)(x + (size_t)row * K);
    float4* rb4 = (float4*)rowbuf;
    const int K4 = K >> 2;
    const int t = threadIdx.x;
    float am = 0.f;
    for (int i = t; i < K4; i += 256) {
        float4 v = xr[i];
        rb4[i] = v;
        am = fmaxf(am, fmaxf(fmaxf(fabsf(v.x), fabsf(v.y)),
                             fmaxf(fabsf(v.z), fabsf(v.w))));
    }
    for (int off = 32; off; off >>= 1) am = fmaxf(am, __shfl_xor(am, off));
    __shared__ float ws[4];
    if ((t & 63) == 0) ws[t >> 6] = am;
    __syncthreads();
    am = fmaxf(fmaxf(ws[0], ws[1]), fmaxf(ws[2], ws[3]));
    const float inv = am > 0.f ? 127.f / am : 0.f;
    if (t == 0) rs[row] = am > 0.f ? am / 127.f : 0.f;
    int* dst = (int*)(xq + (size_t)row * K);
    for (int i = t; i < K4; i += 256) {
        float4 v = rb4[i];
        int a = (int)rintf(v.x * inv), b = (int)rintf(v.y * inv);
        int c = (int)rintf(v.z * inv), d = (int)rintf(v.w * inv);
        dst[i] = (a & 255) | ((b & 255) << 8) | ((c & 255) << 16) | (d << 24);
    }
}

// fallback (large K): two-pass
__global__ __launch_bounds__(256) void quantx_kernel(const float* __restrict__ x,
                                                     char* __restrict__ xq,
                                                     float* __restrict__ rs, int K) {
    const int row = blockIdx.x;
    const float4* xr = (const float4*)(x + (size_t)row * K);
    const int K4 = K >> 2;
    const int t = threadIdx.x;
    float am = 0.f;
    for (int i = t; i < K4; i += 256) {
        float4 v = xr[i];
        am = fmaxf(am, fmaxf(fmaxf(fabsf(v.x), fabsf(v.y)),
                             fmaxf(fabsf(v.z), fabsf(v.w))));
    }
    for (int off = 32; off; off >>= 1) am = fmaxf(am, __shfl_xor(am, off));
    __shared__ float ws[4];
    if ((t & 63) == 0) ws[t >> 6] = am;
    __syncthreads();
    am = fmaxf(fmaxf(ws[0], ws[1]), fmaxf(ws[2], ws[3]));
    const float inv = am > 0.f ? 127.f / am : 0.f;
    if (t == 0) rs[row] = am > 0.f ? am / 127.f : 0.f;
    int* dst = (int*)(xq + (size_t)row * K);
    for (int i = t; i < K4; i += 256) {
        float4 v = xr[i];
        int a = (int)rintf(v.x * inv), b = (int)rintf(v.y * inv);
        int c = (int)rintf(v.z * inv), d = (int)rintf(v.w * inv);
        dst[i] = (a & 255) | ((b & 255) << 8) | ((c & 255) << 16) | (d << 24);
    }
}

// ---------------- qweight int32 -> int8 ----------------
__global__ void convq_kernel(const int* __restrict__ q, char* __restrict__ qb, long n16) {
    long i = (long)blockIdx.x * blockDim.x + threadIdx.x;
    const long stride = (long)gridDim.x * blockDim.x;
    for (; i < n16; i += stride) {
        const int4* p = (const int4*)(q + i * 16);
        int4 a = p[0], b = p[1], c = p[2], d = p[3];
        int4 r;
        r.x = (a.x & 255) | ((a.y & 255) << 8) | ((a.z & 255) << 16) | (a.w << 24);
        r.y = (b.x & 255) | ((b.y & 255) << 8) | ((b.z & 255) << 16) | (b.w << 24);
        r.z = (c.x & 255) | ((c.y & 255) << 8) | ((c.z & 255) << 16) | (c.w << 24);
        r.w = (d.x & 255) | ((d.y & 255) << 8) | ((d.z & 255) << 16) | (d.w << 24);
        ((int4*)qb)[i] = r;
    }
}

// ---------------- 256x256 i8 GEMM, 16x16x64 MFMA (R11-verbatim, best) -------
// C[m,n] = sum_k xq[m,k]*qb[n,k] (i32 exact); out = C * rs[m]*scale[n] + bias[n]
// Measured (R11): GEMM 296us, MfmaUtil 40%, SQ_LDS_BANK_CONFLICT 0.
// R12-R17 perturbations (2/4 blocks-CU, B-direct, fat waves) all regressed:
// this is the structure-local optimum. Keep byte-identical.
__global__ __launch_bounds__(512, 2) void qgemm_i8_kernel(
    const char* __restrict__ A, const char* __restrict__ B,
    const float* __restrict__ rs, const float* __restrict__ scale,
    const float* __restrict__ bias, float* __restrict__ C, int M, int N, int K) {
    extern __shared__ char sm[];

    const int tid  = threadIdx.x;
    const int lane = tid & 63;
    const int w    = tid >> 6;
    const int wr   = w >> 2;                  // 0..1
    const int wc   = w & 3;                   // 0..3
    const int l15  = lane & 15;
    const int l4   = lane >> 4;
    const int r7   = l15 & 7;

    // T1: bijective XCD swizzle (gridDim.x % 8 == 0 by construction)
    const int nwg = gridDim.x;
    const int bid = blockIdx.x;
    const int swz = (bid & 7) * (nwg >> 3) + (bid >> 3);
    const int nbx = N >> 8;
    const int m0  = (swz / nbx) << 8;
    const int n0  = (swz % nbx) << 8;

    // staging: chunk c -> r=c>>3, s=(c&7)^(r&7); src byte = r*K + s*16
    const int c0 = tid, c1 = tid + 512;
    const size_t inv0 = (size_t)(c0 >> 3) * K + (size_t)((((c0 & 7) ^ ((c0 >> 3) & 7))) << 4);
    const size_t inv1 = (size_t)(c1 >> 3) * K + (size_t)((((c1 & 7) ^ ((c1 >> 3) & 7))) << 4);
    const int ldst0 = w << 10;
    const int ldst1 = (w << 10) + 8192;

#define STAGE(ldsHalf, gsrc) do {                         \
        gload_lds16((gsrc) + inv0, (ldsHalf) + ldst0);    \
        gload_lds16((gsrc) + inv1, (ldsHalf) + ldst1); } while (0)

    // fragment read offsets (bytes)
    const int aRow0 = (wr * 128 + l15) * 128;  // + m*2048
    const int bRow0 = (wc * 64 + l15) * 128;   // + n*2048
    const int sl0   = ((0 + l4) ^ r7) << 4;    // kk=0: k-bytes 0-63
    const int sl1   = ((4 + l4) ^ r7) << 4;    // kk=1: k-bytes 64-127

    const char* pA = A + (size_t)m0 * K;
    const char* pB = B + (size_t)n0 * K;
    const size_t hK = (size_t)128 * K;
    const int NT = K >> 7;                     // 128 bytes of K per tile

    i32x4 acc[8][4];
#pragma unroll
    for (int m = 0; m < 8; ++m)
#pragma unroll
        for (int n = 0; n < 4; ++n) acc[m][n] = (i32x4){0, 0, 0, 0};

#define RD_A(DST, BUF, MB)                                                     \
    _Pragma("unroll") for (int m = 0; m < 4; ++m) {                            \
        (DST)[m][0] = *(const i8x16*)((BUF) + aRow0 + ((MB) + m) * 2048 + sl0); \
        (DST)[m][1] = *(const i8x16*)((BUF) + aRow0 + ((MB) + m) * 2048 + sl1); }
#define RD_B(DST, BUF, NB)                                                     \
    _Pragma("unroll") for (int n = 0; n < 2; ++n) {                            \
        (DST)[n][0] = *(const i8x16*)((BUF) + bRow0 + ((NB) + n) * 2048 + sl0); \
        (DST)[n][1] = *(const i8x16*)((BUF) + bRow0 + ((NB) + n) * 2048 + sl1); }
#define MFMA8(AF, BF, MB, NB)                                                  \
    _Pragma("unroll") for (int kk = 0; kk < 2; ++kk)                           \
    _Pragma("unroll") for (int m = 0; m < 4; ++m)                              \
    _Pragma("unroll") for (int n = 0; n < 2; ++n)                              \
        acc[(MB) + m][(NB) + n] = __builtin_amdgcn_mfma_i32_16x16x64_i8(       \
            (AF)[m][kk], (BF)[n][kk], acc[(MB) + m][(NB) + n], 0, 0, 0);
#define LGKM(N) do { asm volatile("s_waitcnt lgkmcnt(" #N ")" ::: "memory");   \
                     __builtin_amdgcn_sched_barrier(0); } while (0)

    i8x16 aF0[4][2], aF1[4][2], bF01[2][2], bF23[2][2];

    // ---- prologue: tile0 (4 halves) + B0/B1(tile1) [12 loads] ----
    STAGE(sm + 0,      pA);            // A0(0)
    STAGE(sm + 16384,  pA + hK);       // A1(0)
    STAGE(sm + 65536,  pB);            // B0(0)
    STAGE(sm + 81920,  pB + hK);       // B1(0)
    if (NT > 1) {
        STAGE(sm + 98304,  pB + 128);        // B0(1)
        STAGE(sm + 114688, pB + hK + 128);   // B1(1)
        asm volatile("s_waitcnt vmcnt(4)" ::: "memory");  // tile0 halves landed
    } else {
        asm volatile("s_waitcnt vmcnt(0)" ::: "memory");
    }
    __builtin_amdgcn_s_barrier();
    __builtin_amdgcn_sched_barrier(0);
    RD_A(aF0, sm, 0);                  // tile0 mh0   (8 reads)
    RD_B(bF01, sm + 65536, 0);         // tile0 n0,n1 (4 reads)
    RD_B(bF23, sm + 65536, 2);         // tile0 n2,n3 (4 reads)

    for (int t = 0; t < NT; ++t) {
        const int cur = t & 1;
        char* Ab = sm + cur * 32768;
        char* Bb = sm + 65536 + cur * 32768;
        char* An = sm + (cur ^ 1) * 32768;
        char* Bn = sm + 65536 + (cur ^ 1) * 32768;
        const int k1 = (t + 1) << 7;
        const int k2 = (t + 2) << 7;

        // ---- P0: stage A0+A1(t+1)->next-A (after B2(t-1): WAR-safe);
        //          wait aF0/bF01 (12 oldest); MFMA q(0,0) ----
        if (t + 1 < NT) {
            STAGE(An,         pA + k1);
            STAGE(An + 16384, pA + hK + k1);
        }
        LGKM(4);                       // aF0,bF01 ready; bF23 still in flight
        __builtin_amdgcn_s_setprio(1);
        MFMA8(aF0, bF01, 0, 0);
        __builtin_amdgcn_s_setprio(0);

        // ---- P1: issue aF1; wait bF23; MFMA; vmcnt(0); BARRIER B1 ----
        RD_A(aF1, Ab, 4);
        LGKM(8);                       // bF23 ready (aF1 in flight)
        __builtin_amdgcn_s_setprio(1);
        MFMA8(aF0, bF23, 0, 2);
        __builtin_amdgcn_s_setprio(0);
        asm volatile("s_waitcnt vmcnt(0)" ::: "memory");
        __builtin_amdgcn_s_barrier();  // B1: publish ALL of tile t+1

        // ---- P2: stage B0(t+2)->cur-B; wait aF1; MFMA (old bF01);
        //          then early-read t+1 mh0/n01 ----
        if (t + 2 < NT) STAGE(Bb, pB + k2);
        LGKM(0);                       // aF1 ready
        __builtin_amdgcn_s_setprio(1);
        MFMA8(aF1, bF01, 4, 0);
        __builtin_amdgcn_s_setprio(0);
        if (t + 1 < NT) {
            RD_A(aF0, An, 0);          // t+1 mh0 (published at B1)
            RD_B(bF01, Bn, 0);         // t+1 n0,n1 (published at B1)
        }

        // ---- P3: stage B1(t+2); MFMA q(1,1) with OLD bF23 FIRST;
        //          then early-read bF23(t+1); BARRIER B2 (no vmcnt) ----
        if (t + 2 < NT) STAGE(Bb + 16384, pB + hK + k2);
        __builtin_amdgcn_s_setprio(1);
        MFMA8(aF1, bF23, 4, 2);        // consumes tile t's bF23
        __builtin_amdgcn_s_setprio(0);
        if (t + 1 < NT) RD_B(bF23, Bn, 2);  // t+1 n2,n3 (published at B1)
        __builtin_amdgcn_s_barrier();  // B2: exec-sync before next P0 A-staging
    }

    // ---- epilogue: out = acc * (rs[row]*scale[col]) + bias[col] ----
    // C/D 16x16 layout (shape-determined, m121-128): col=l15, row=l4*4+j
#pragma unroll
    for (int n = 0; n < 4; ++n) {
        const int col = n0 + wc * 64 + n * 16 + l15;
        const float sc = scale[col];
        const float bs = bias[col];
#pragma unroll
        for (int m = 0; m < 8; ++m) {
            const int row0 = m0 + wr * 128 + m * 16 + l4 * 4;
#pragma unroll
            for (int j = 0; j < 4; ++j)
                C[(size_t)(row0 + j) * N + col] =
                    (float)acc[m][n][j] * (rs[row0 + j] * sc) + bs;
        }
    }
#undef STAGE
#undef RD_A
#undef RD_B
#undef MFMA8
#undef LGKM
}

// ---------------- fallback (shape mismatch): 2-phase bf16, on-the-fly ----
__global__ __launch_bounds__(256) void qgemm_fb_kernel(
    const float* __restrict__ Af, const int* __restrict__ Bi,
    const float* __restrict__ scale, const float* __restrict__ bias,
    float* __restrict__ C, int M, int N, int K) {
    constexpr int BK = 64;
    __shared__ unsigned short lA[128 * BK];
    __shared__ unsigned short lB[128 * BK];
    const int t = threadIdx.x, lane = t & 63, w = t >> 6;
    const int wr = w >> 1, wc = w & 1;
    const int m0 = blockIdx.y * 128, n0 = blockIdx.x * 128;
    const int l15 = lane & 15, l4 = lane >> 4;
    f32x4 acc[4][4];
#pragma unroll
    for (int m = 0; m < 4; ++m)
#pragma unroll
        for (int n = 0; n < 4; ++n) acc[m][n] = (f32x4){0.f, 0.f, 0.f, 0.f};
    for (int k0 = 0; k0 < K; k0 += BK) {
        __syncthreads();
#pragma unroll
        for (int i = 0; i < 4; ++i) {
            const int off = i * 4096 + w * 1024 + lane * 16;
            const int row = off >> 7;
            const int col = (off & 127) >> 1;
            const float* pa = Af + (size_t)(m0 + row) * K + k0 + col;
            float4 a0 = *(const float4*)pa;
            float4 a1 = *(const float4*)(pa + 4);
            ushort8 va;
            va[0] = f32_to_bf16(a0.x); va[1] = f32_to_bf16(a0.y);
            va[2] = f32_to_bf16(a0.z); va[3] = f32_to_bf16(a0.w);
            va[4] = f32_to_bf16(a1.x); va[5] = f32_to_bf16(a1.y);
            va[6] = f32_to_bf16(a1.z); va[7] = f32_to_bf16(a1.w);
            *(ushort8*)((char*)lA + off) = va;
            const int* pb = Bi + (size_t)(n0 + row) * K + k0 + col;
            int4 b0 = *(const int4*)pb;
            int4 b1 = *(const int4*)(pb + 4);
            ushort8 vb;
            vb[0] = f32_to_bf16((float)b0.x); vb[1] = f32_to_bf16((float)b0.y);
            vb[2] = f32_to_bf16((float)b0.z); vb[3] = f32_to_bf16((float)b0.w);
            vb[4] = f32_to_bf16((float)b1.x); vb[5] = f32_to_bf16((float)b1.y);
            vb[6] = f32_to_bf16((float)b1.z); vb[7] = f32_to_bf16((float)b1.w);
            *(ushort8*)((char*)lB + off) = vb;
        }
        __syncthreads();
#pragma unroll
        for (int kk = 0; kk < BK; kk += 32) {
            bf16x8 af[4], bfr[4];
#pragma unroll
            for (int m = 0; m < 4; ++m)
                af[m] = *(const bf16x8*)&lA[(wr * 64 + m * 16 + l15) * BK + kk + l4 * 8];
#pragma unroll
            for (int n = 0; n < 4; ++n)
                bfr[n] = *(const bf16x8*)&lB[(wc * 64 + n * 16 + l15) * BK + kk + l4 * 8];
#pragma unroll
            for (int m = 0; m < 4; ++m)
#pragma unroll
                for (int n = 0; n < 4; ++n)
                    acc[m][n] = __builtin_amdgcn_mfma_f32_16x16x32_bf16(
                        af[m], bfr[n], acc[m][n], 0, 0, 0);
        }
    }
#pragma unroll
    for (int n = 0; n < 4; ++n) {
        const int col = n0 + wc * 64 + n * 16 + l15;
        const float sc = scale[col], bs = bias[col];
#pragma unroll
        for (int m = 0; m < 4; ++m) {
            const int row0 = m0 + wr * 64 + m * 16 + l4 * 4;
#pragma unroll
            for (int j = 0; j < 4; ++j)
                C[(size_t)(row0 + j) * N + col] = fmaf(acc[m][n][j], sc, bs);
        }
    }
}

extern "C" void kernel_launch(void* const* d_in, const int* in_sizes, int n_in,
                              void* d_out, int out_size, void* d_ws, size_t ws_size,
                              hipStream_t stream) {
    const float* x     = (const float*)d_in[0];
    const int*   q     = (const int*)d_in[1];
    const float* scale = (const float*)d_in[2];
    const float* bias  = (const float*)d_in[3];
    float*       out   = (float*)d_out;

    const int K = in_sizes[2];
    const int N = in_sizes[1] / K;
    const int M = in_sizes[0] / K;

    const size_t xq_b = (size_t)M * K;
    const size_t qb_b = (size_t)N * K;
    const size_t need = xq_b + qb_b + (size_t)M * 4;
    const int nwg = (M / 256) * (N / 256);

    if (ws_size >= need && (M % 256) == 0 && (N % 256) == 0 &&
        (K % 128) == 0 && K >= 256 && (nwg % 8) == 0) {
        char*  xq = (char*)d_ws;
        char*  qb = xq + xq_b;
        float* rs = (float*)(qb + qb_b);
        if ((size_t)K * 4 <= 65536) {
            quantx_lds_kernel<<<M, 256, (size_t)K * 4, stream>>>(x, xq, rs, K);
        } else {
            quantx_kernel<<<M, 256, 0, stream>>>(x, xq, rs, K);
        }
        convq_kernel<<<2048, 256, 0, stream>>>(q, qb, (long)(qb_b / 16));
        qgemm_i8_kernel<<<nwg, 512, 131072, stream>>>(xq, qb, rs, scale, bias,
                                                      out, M, N, K);
    } else {
        dim3 grid(N / 128, M / 128);
        qgemm_fb_kernel<<<grid, 256, 0, stream>>>(x, q, scale, bias, out, M, N, K);
    }
}

// Round 19
// 369.714 us; speedup vs baseline: 1.6812x; 1.0066x over previous
//
#include <hip/hip_runtime.h>

typedef __attribute__((ext_vector_type(4))) int  i8x16;   // 16 packed int8 (4 VGPR MFMA operand)
typedef __attribute__((ext_vector_type(4))) int  i32x4;   // 16x16 i32 accumulator
typedef __attribute__((ext_vector_type(8))) short bf16x8;
typedef __attribute__((ext_vector_type(8))) unsigned short ushort8;
typedef __attribute__((ext_vector_type(4))) float f32x4;

__device__ __forceinline__ unsigned short f32_to_bf16(float f) {
    union { float f; unsigned int u; } v;
    v.f = f;
    unsigned int r = v.u + (0x7fffu + ((v.u >> 16) & 1u));
    return (unsigned short)(r >> 16);
}

__device__ __forceinline__ void gload_lds16(const void* g, void* l) {
    __builtin_amdgcn_global_load_lds(
        (const __attribute__((address_space(1))) unsigned int*)g,
        (__attribute__((address_space(3))) unsigned int*)l, 16, 0, 0);
}

// ---------------- fused pre-pass: x->i8 row quant (blocks < M) +
//                  qweight i32->i8 pack (blocks >= M) -----------------------
// Fusing overlaps the two independent memory streams (419 MB total) in one
// dispatch instead of two serial ones.
__global__ __launch_bounds__(256) void prep_kernel(
    const float* __restrict__ x, char* __restrict__ xq, float* __restrict__ rs,
    const int* __restrict__ q, char* __restrict__ qb, long n16, int K, int M) {
    extern __shared__ float rowbuf[];          // K floats (quant path)
    const int b = blockIdx.x;
    const int t = threadIdx.x;
    if (b < M) {
        // ---- per-row symmetric int8 quantization, single global read ----
        const float4* xr = (const float4*)(x + (size_t)b * K);
        float4* rb4 = (float4*)rowbuf;
        const int K4 = K >> 2;
        float am = 0.f;
        for (int i = t; i < K4; i += 256) {
            float4 v = xr[i];
            rb4[i] = v;
            am = fmaxf(am, fmaxf(fmaxf(fabsf(v.x), fabsf(v.y)),
                                 fmaxf(fabsf(v.z), fabsf(v.w))));
        }
        for (int off = 32; off; off >>= 1) am = fmaxf(am, __shfl_xor(am, off));
        __shared__ float ws[4];
        if ((t & 63) == 0) ws[t >> 6] = am;
        __syncthreads();
        am = fmaxf(fmaxf(ws[0], ws[1]), fmaxf(ws[2], ws[3]));
        const float inv = am > 0.f ? 127.f / am : 0.f;
        if (t == 0) rs[b] = am > 0.f ? am / 127.f : 0.f;
        int* dst = (int*)(xq + (size_t)b * K);
        for (int i = t; i < K4; i += 256) {
            float4 v = rb4[i];
            int a = (int)rintf(v.x * inv), b2 = (int)rintf(v.y * inv);
            int c = (int)rintf(v.z * inv), d = (int)rintf(v.w * inv);
            dst[i] = (a & 255) | ((b2 & 255) << 8) | ((c & 255) << 16) | (d << 24);
        }
    } else {
        // ---- qweight int32 -> packed int8 ----
        const int nb = gridDim.x - M;          // conv blocks
        long i = (long)(b - M) * 256 + t;
        const long stride = (long)nb * 256;
        for (; i < n16; i += stride) {
            const int4* p = (const int4*)(q + i * 16);
            int4 a = p[0], b2 = p[1], c = p[2], d = p[3];
            int4 r;
            r.x = (a.x & 255) | ((a.y & 255) << 8) | ((a.z & 255) << 16) | (a.w << 24);
            r.y = (b2.x & 255) | ((b2.y & 255) << 8) | ((b2.z & 255) << 16) | (b2.w << 24);
            r.z = (c.x & 255) | ((c.y & 255) << 8) | ((c.z & 255) << 16) | (c.w << 24);
            r.w = (d.x & 255) | ((d.y & 255) << 8) | ((d.z & 255) << 16) | (d.w << 24);
            ((int4*)qb)[i] = r;
        }
    }
}

// fallback pre-kernels (large K / odd shapes)
__global__ __launch_bounds__(256) void quantx_kernel(const float* __restrict__ x,
                                                     char* __restrict__ xq,
                                                     float* __restrict__ rs, int K) {
    const int row = blockIdx.x;
    const float4* xr = (const float4*)(x + (size_t)row * K);
    const int K4 = K >> 2;
    const int t = threadIdx.x;
    float am = 0.f;
    for (int i = t; i < K4; i += 256) {
        float4 v = xr[i];
        am = fmaxf(am, fmaxf(fmaxf(fabsf(v.x), fabsf(v.y)),
                             fmaxf(fabsf(v.z), fabsf(v.w))));
    }
    for (int off = 32; off; off >>= 1) am = fmaxf(am, __shfl_xor(am, off));
    __shared__ float ws[4];
    if ((t & 63) == 0) ws[t >> 6] = am;
    __syncthreads();
    am = fmaxf(fmaxf(ws[0], ws[1]), fmaxf(ws[2], ws[3]));
    const float inv = am > 0.f ? 127.f / am : 0.f;
    if (t == 0) rs[row] = am > 0.f ? am / 127.f : 0.f;
    int* dst = (int*)(xq + (size_t)row * K);
    for (int i = t; i < K4; i += 256) {
        float4 v = xr[i];
        int a = (int)rintf(v.x * inv), b = (int)rintf(v.y * inv);
        int c = (int)rintf(v.z * inv), d = (int)rintf(v.w * inv);
        dst[i] = (a & 255) | ((b & 255) << 8) | ((c & 255) << 16) | (d << 24);
    }
}

__global__ void convq_kernel(const int* __restrict__ q, char* __restrict__ qb, long n16) {
    long i = (long)blockIdx.x * blockDim.x + threadIdx.x;
    const long stride = (long)gridDim.x * blockDim.x;
    for (; i < n16; i += stride) {
        const int4* p = (const int4*)(q + i * 16);
        int4 a = p[0], b = p[1], c = p[2], d = p[3];
        int4 r;
        r.x = (a.x & 255) | ((a.y & 255) << 8) | ((a.z & 255) << 16) | (a.w << 24);
        r.y = (b.x & 255) | ((b.y & 255) << 8) | ((b.z & 255) << 16) | (b.w << 24);
        r.z = (c.x & 255) | ((c.y & 255) << 8) | ((c.z & 255) << 16) | (c.w << 24);
        r.w = (d.x & 255) | ((d.y & 255) << 8) | ((d.z & 255) << 16) | (d.w << 24);
        ((int4*)qb)[i] = r;
    }
}

// ---------------- 256x256 i8 GEMM, 16x16x64 MFMA (R11-verbatim, best) -------
// C[m,n] = sum_k xq[m,k]*qb[n,k] (i32 exact); out = C * rs[m]*scale[n] + bias[n]
// Measured (R11/R18): GEMM 296-300us, MfmaUtil ~39%, SQ_LDS_BANK_CONFLICT 0.
// R12-R17 perturbations (2/4 blocks-CU, B-direct, fat waves, schedules) all
// regressed or null: structure-local optimum. Keep byte-identical.
__global__ __launch_bounds__(512, 2) void qgemm_i8_kernel(
    const char* __restrict__ A, const char* __restrict__ B,
    const float* __restrict__ rs, const float* __restrict__ scale,
    const float* __restrict__ bias, float* __restrict__ C, int M, int N, int K) {
    extern __shared__ char sm[];

    const int tid  = threadIdx.x;
    const int lane = tid & 63;
    const int w    = tid >> 6;
    const int wr   = w >> 2;                  // 0..1
    const int wc   = w & 3;                   // 0..3
    const int l15  = lane & 15;
    const int l4   = lane >> 4;
    const int r7   = l15 & 7;

    // T1: bijective XCD swizzle (gridDim.x % 8 == 0 by construction)
    const int nwg = gridDim.x;
    const int bid = blockIdx.x;
    const int swz = (bid & 7) * (nwg >> 3) + (bid >> 3);
    const int nbx = N >> 8;
    const int m0  = (swz / nbx) << 8;
    const int n0  = (swz % nbx) << 8;

    // staging: chunk c -> r=c>>3, s=(c&7)^(r&7); src byte = r*K + s*16
    const int c0 = tid, c1 = tid + 512;
    const size_t inv0 = (size_t)(c0 >> 3) * K + (size_t)((((c0 & 7) ^ ((c0 >> 3) & 7))) << 4);
    const size_t inv1 = (size_t)(c1 >> 3) * K + (size_t)((((c1 & 7) ^ ((c1 >> 3) & 7))) << 4);
    const int ldst0 = w << 10;
    const int ldst1 = (w << 10) + 8192;

#define STAGE(ldsHalf, gsrc) do {                         \
        gload_lds16((gsrc) + inv0, (ldsHalf) + ldst0);    \
        gload_lds16((gsrc) + inv1, (ldsHalf) + ldst1); } while (0)

    // fragment read offsets (bytes)
    const int aRow0 = (wr * 128 + l15) * 128;  // + m*2048
    const int bRow0 = (wc * 64 + l15) * 128;   // + n*2048
    const int sl0   = ((0 + l4) ^ r7) << 4;    // kk=0: k-bytes 0-63
    const int sl1   = ((4 + l4) ^ r7) << 4;    // kk=1: k-bytes 64-127

    const char* pA = A + (size_t)m0 * K;
    const char* pB = B + (size_t)n0 * K;
    const size_t hK = (size_t)128 * K;
    const int NT = K >> 7;                     // 128 bytes of K per tile

    i32x4 acc[8][4];
#pragma unroll
    for (int m = 0; m < 8; ++m)
#pragma unroll
        for (int n = 0; n < 4; ++n) acc[m][n] = (i32x4){0, 0, 0, 0};

#define RD_A(DST, BUF, MB)                                                     \
    _Pragma("unroll") for (int m = 0; m < 4; ++m) {                            \
        (DST)[m][0] = *(const i8x16*)((BUF) + aRow0 + ((MB) + m) * 2048 + sl0); \
        (DST)[m][1] = *(const i8x16*)((BUF) + aRow0 + ((MB) + m) * 2048 + sl1); }
#define RD_B(DST, BUF, NB)                                                     \
    _Pragma("unroll") for (int n = 0; n < 2; ++n) {                            \
        (DST)[n][0] = *(const i8x16*)((BUF) + bRow0 + ((NB) + n) * 2048 + sl0); \
        (DST)[n][1] = *(const i8x16*)((BUF) + bRow0 + ((NB) + n) * 2048 + sl1); }
#define MFMA8(AF, BF, MB, NB)                                                  \
    _Pragma("unroll") for (int kk = 0; kk < 2; ++kk)                           \
    _Pragma("unroll") for (int m = 0; m < 4; ++m)                              \
    _Pragma("unroll") for (int n = 0; n < 2; ++n)                              \
        acc[(MB) + m][(NB) + n] = __builtin_amdgcn_mfma_i32_16x16x64_i8(       \
            (AF)[m][kk], (BF)[n][kk], acc[(MB) + m][(NB) + n], 0, 0, 0);
#define LGKM(N) do { asm volatile("s_waitcnt lgkmcnt(" #N ")" ::: "memory");   \
                     __builtin_amdgcn_sched_barrier(0); } while (0)

    i8x16 aF0[4][2], aF1[4][2], bF01[2][2], bF23[2][2];

    // ---- prologue: tile0 (4 halves) + B0/B1(tile1) [12 loads] ----
    STAGE(sm + 0,      pA);            // A0(0)
    STAGE(sm + 16384,  pA + hK);       // A1(0)
    STAGE(sm + 65536,  pB);            // B0(0)
    STAGE(sm + 81920,  pB + hK);       // B1(0)
    if (NT > 1) {
        STAGE(sm + 98304,  pB + 128);        // B0(1)
        STAGE(sm + 114688, pB + hK + 128);   // B1(1)
        asm volatile("s_waitcnt vmcnt(4)" ::: "memory");  // tile0 halves landed
    } else {
        asm volatile("s_waitcnt vmcnt(0)" ::: "memory");
    }
    __builtin_amdgcn_s_barrier();
    __builtin_amdgcn_sched_barrier(0);
    RD_A(aF0, sm, 0);                  // tile0 mh0   (8 reads)
    RD_B(bF01, sm + 65536, 0);         // tile0 n0,n1 (4 reads)
    RD_B(bF23, sm + 65536, 2);         // tile0 n2,n3 (4 reads)

    for (int t = 0; t < NT; ++t) {
        const int cur = t & 1;
        char* Ab = sm + cur * 32768;
        char* Bb = sm + 65536 + cur * 32768;
        char* An = sm + (cur ^ 1) * 32768;
        char* Bn = sm + 65536 + (cur ^ 1) * 32768;
        const int k1 = (t + 1) << 7;
        const int k2 = (t + 2) << 7;

        // ---- P0: stage A0+A1(t+1)->next-A (after B2(t-1): WAR-safe);
        //          wait aF0/bF01 (12 oldest); MFMA q(0,0) ----
        if (t + 1 < NT) {
            STAGE(An,         pA + k1);
            STAGE(An + 16384, pA + hK + k1);
        }
        LGKM(4);                       // aF0,bF01 ready; bF23 still in flight
        __builtin_amdgcn_s_setprio(1);
        MFMA8(aF0, bF01, 0, 0);
        __builtin_amdgcn_s_setprio(0);

        // ---- P1: issue aF1; wait bF23; MFMA; vmcnt(0); BARRIER B1 ----
        RD_A(aF1, Ab, 4);
        LGKM(8);                       // bF23 ready (aF1 in flight)
        __builtin_amdgcn_s_setprio(1);
        MFMA8(aF0, bF23, 0, 2);
        __builtin_amdgcn_s_setprio(0);
        asm volatile("s_waitcnt vmcnt(0)" ::: "memory");
        __builtin_amdgcn_s_barrier();  // B1: publish ALL of tile t+1

        // ---- P2: stage B0(t+2)->cur-B; wait aF1; MFMA (old bF01);
        //          then early-read t+1 mh0/n01 ----
        if (t + 2 < NT) STAGE(Bb, pB + k2);
        LGKM(0);                       // aF1 ready
        __builtin_amdgcn_s_setprio(1);
        MFMA8(aF1, bF01, 4, 0);
        __builtin_amdgcn_s_setprio(0);
        if (t + 1 < NT) {
            RD_A(aF0, An, 0);          // t+1 mh0 (published at B1)
            RD_B(bF01, Bn, 0);         // t+1 n0,n1 (published at B1)
        }

        // ---- P3: stage B1(t+2); MFMA q(1,1) with OLD bF23 FIRST;
        //          then early-read bF23(t+1); BARRIER B2 (no vmcnt) ----
        if (t + 2 < NT) STAGE(Bb + 16384, pB + hK + k2);
        __builtin_amdgcn_s_setprio(1);
        MFMA8(aF1, bF23, 4, 2);        // consumes tile t's bF23
        __builtin_amdgcn_s_setprio(0);
        if (t + 1 < NT) RD_B(bF23, Bn, 2);  // t+1 n2,n3 (published at B1)
        __builtin_amdgcn_s_barrier();  // B2: exec-sync before next P0 A-staging
    }

    // ---- epilogue: out = acc * (rs[row]*scale[col]) + bias[col] ----
    // C/D 16x16 layout (shape-determined, m121-128): col=l15, row=l4*4+j
#pragma unroll
    for (int n = 0; n < 4; ++n) {
        const int col = n0 + wc * 64 + n * 16 + l15;
        const float sc = scale[col];
        const float bs = bias[col];
#pragma unroll
        for (int m = 0; m < 8; ++m) {
            const int row0 = m0 + wr * 128 + m * 16 + l4 * 4;
#pragma unroll
            for (int j = 0; j < 4; ++j)
                C[(size_t)(row0 + j) * N + col] =
                    (float)acc[m][n][j] * (rs[row0 + j] * sc) + bs;
        }
    }
#undef STAGE
#undef RD_A
#undef RD_B
#undef MFMA8
#undef LGKM
}

// ---------------- fallback (shape mismatch): 2-phase bf16, on-the-fly ----
__global__ __launch_bounds__(256) void qgemm_fb_kernel(
    const float* __restrict__ Af, const int* __restrict__ Bi,
    const float* __restrict__ scale, const float* __restrict__ bias,
    float* __restrict__ C, int M, int N, int K) {
    constexpr int BK = 64;
    __shared__ unsigned short lA[128 * BK];
    __shared__ unsigned short lB[128 * BK];
    const int t = threadIdx.x, lane = t & 63, w = t >> 6;
    const int wr = w >> 1, wc = w & 1;
    const int m0 = blockIdx.y * 128, n0 = blockIdx.x * 128;
    const int l15 = lane & 15, l4 = lane >> 4;
    f32x4 acc[4][4];
#pragma unroll
    for (int m = 0; m < 4; ++m)
#pragma unroll
        for (int n = 0; n < 4; ++n) acc[m][n] = (f32x4){0.f, 0.f, 0.f, 0.f};
    for (int k0 = 0; k0 < K; k0 += BK) {
        __syncthreads();
#pragma unroll
        for (int i = 0; i < 4; ++i) {
            const int off = i * 4096 + w * 1024 + lane * 16;
            const int row = off >> 7;
            const int col = (off & 127) >> 1;
            const float* pa = Af + (size_t)(m0 + row) * K + k0 + col;
            float4 a0 = *(const float4*)pa;
            float4 a1 = *(const float4*)(pa + 4);
            ushort8 va;
            va[0] = f32_to_bf16(a0.x); va[1] = f32_to_bf16(a0.y);
            va[2] = f32_to_bf16(a0.z); va[3] = f32_to_bf16(a0.w);
            va[4] = f32_to_bf16(a1.x); va[5] = f32_to_bf16(a1.y);
            va[6] = f32_to_bf16(a1.z); va[7] = f32_to_bf16(a1.w);
            *(ushort8*)((char*)lA + off) = va;
            const int* pb = Bi + (size_t)(n0 + row) * K + k0 + col;
            int4 b0 = *(const int4*)pb;
            int4 b1 = *(const int4*)(pb + 4);
            ushort8 vb;
            vb[0] = f32_to_bf16((float)b0.x); vb[1] = f32_to_bf16((float)b0.y);
            vb[2] = f32_to_bf16((float)b0.z); vb[3] = f32_to_bf16((float)b0.w);
            vb[4] = f32_to_bf16((float)b1.x); vb[5] = f32_to_bf16((float)b1.y);
            vb[6] = f32_to_bf16((float)b1.z); vb[7] = f32_to_bf16((float)b1.w);
            *(ushort8*)((char*)lB + off) = vb;
        }
        __syncthreads();
#pragma unroll
        for (int kk = 0; kk < BK; kk += 32) {
            bf16x8 af[4], bfr[4];
#pragma unroll
            for (int m = 0; m < 4; ++m)
                af[m] = *(const bf16x8*)&lA[(wr * 64 + m * 16 + l15) * BK + kk + l4 * 8];
#pragma unroll
            for (int n = 0; n < 4; ++n)
                bfr[n] = *(const bf16x8*)&lB[(wc * 64 + n * 16 + l15) * BK + kk + l4 * 8];
#pragma unroll
            for (int m = 0; m < 4; ++m)
#pragma unroll
                for (int n = 0; n < 4; ++n)
                    acc[m][n] = __builtin_amdgcn_mfma_f32_16x16x32_bf16(
                        af[m], bfr[n], acc[m][n], 0, 0, 0);
        }
    }
#pragma unroll
    for (int n = 0; n < 4; ++n) {
        const int col = n0 + wc * 64 + n * 16 + l15;
        const float sc = scale[col], bs = bias[col];
#pragma unroll
        for (int m = 0; m < 4; ++m) {
            const int row0 = m0 + wr * 64 + m * 16 + l4 * 4;
#pragma unroll
            for (int j = 0; j < 4; ++j)
                C[(size_t)(row0 + j) * N + col] = fmaf(acc[m][n][j], sc, bs);
        }
    }
}

extern "C" void kernel_launch(void* const* d_in, const int* in_sizes, int n_in,
                              void* d_out, int out_size, void* d_ws, size_t ws_size,
                              hipStream_t stream) {
    const float* x     = (const float*)d_in[0];
    const int*   q     = (const int*)d_in[1];
    const float* scale = (const float*)d_in[2];
    const float* bias  = (const float*)d_in[3];
    float*       out   = (float*)d_out;

    const int K = in_sizes[2];
    const int N = in_sizes[1] / K;
    const int M = in_sizes[0] / K;

    const size_t xq_b = (size_t)M * K;
    const size_t qb_b = (size_t)N * K;
    const size_t need = xq_b + qb_b + (size_t)M * 4;
    const int nwg = (M / 256) * (N / 256);

    if (ws_size >= need && (M % 256) == 0 && (N % 256) == 0 &&
        (K % 128) == 0 && K >= 256 && (nwg % 8) == 0) {
        char*  xq = (char*)d_ws;
        char*  qb = xq + xq_b;
        float* rs = (float*)(qb + qb_b);
        if ((size_t)K * 4 <= 65536) {
            prep_kernel<<<M + 2048, 256, (size_t)K * 4, stream>>>(
                x, xq, rs, q, qb, (long)(qb_b / 16), K, M);
        } else {
            quantx_kernel<<<M, 256, 0, stream>>>(x, xq, rs, K);
            convq_kernel<<<2048, 256, 0, stream>>>(q, qb, (long)(qb_b / 16));
        }
        qgemm_i8_kernel<<<nwg, 512, 131072, stream>>>(xq, qb, rs, scale, bias,
                                                      out, M, N, K);
    } else {
        dim3 grid(N / 128, M / 128);
        qgemm_fb_kernel<<<grid, 256, 0, stream>>>(x, q, scale, bias, out, M, N, K);
    }
}